// Round 21
// baseline (231.861 us; speedup 1.0000x reference)
//
#include <hip/hip_runtime.h>
#include <stdint.h>

// ---------- types ----------
typedef short bf16x8 __attribute__((ext_vector_type(8)));
typedef float f32x4  __attribute__((ext_vector_type(4)));
typedef float f32x16 __attribute__((ext_vector_type(16)));
typedef int   i32x2  __attribute__((ext_vector_type(2)));

#define EPS_RMS 1.1920929e-07f
#define INV_SQRT_HD 0.08838834764831845f  // 1/sqrt(128)
#define NEGBIG (-3.0e38f)

// f32 -> bf16 bits, round-to-nearest-even (scalar, epilogue/convert use)
__device__ __forceinline__ short f2bf(float f) {
    uint32_t u = __float_as_uint(f);
    u += 0x7fffu + ((u >> 16) & 1u);
    return (short)(u >> 16);
}

// packed f32x2 -> bf16x2 in one VALU op (T12 recipe; no builtin on gfx950)
__device__ __forceinline__ unsigned int cvtpk(float lo, float hi) {
    unsigned int r;
    asm("v_cvt_pk_bf16_f32 %0, %1, %2" : "=v"(r) : "v"(lo), "v"(hi));
    return r;
}

// v_permlane32_swap_b32: x = {a.lo | b.lo->hi}, y = {a.hi->lo | b.hi}
__device__ __forceinline__ void halfswap(unsigned int a, unsigned int b,
                                         unsigned int& x, unsigned int& y) {
    i32x2 r = __builtin_amdgcn_permlane32_swap((int)a, (int)b, false, false);
    x = (unsigned int)r.x;
    y = (unsigned int)r.y;
}

using gld_t = const __attribute__((address_space(1))) unsigned int*;
using lds_t = __attribute__((address_space(3))) unsigned int*;

// async global->LDS, 16 bytes per lane (lane i lands at ldsbase + i*16)
__device__ __forceinline__ void glds16(const short* g, short* l) {
    __builtin_amdgcn_global_load_lds((gld_t)g, (lds_t)l, 16, 0, 0);
}

// ---------- kernel 1: f32 -> bf16 convert (vectorized x4) ----------
__global__ void cvt_f32_bf16(const float* __restrict__ in, short* __restrict__ out, int n) {
    int i = (blockIdx.x * blockDim.x + threadIdx.x) * 4;
    int stride = gridDim.x * blockDim.x * 4;
    for (; i < n; i += stride) {
        float4 v = *(const float4*)(in + i);
        short4 o;
        o.x = f2bf(v.x); o.y = f2bf(v.y); o.z = f2bf(v.z); o.w = f2bf(v.w);
        *(short4*)(out + i) = o;
    }
}

// ---------- kernel 2: C[M,N] = A[M,K] * Bw[N,K]^T  (bf16 in, f32 out) ----------
// 8-wave (512-thread) 128x128 block, wave tile 32x64; double-buffered LDS,
// stage tile t+1 BEFORE computing tile t, ONE barrier per K-step. Staging is
// a single glds16 per operand tile (512 lanes x 16B = 128x32 bf16).
// T1 XCD swizzle: bijective block->tile remap (requires nwg % 8 == 0; both
// grids satisfy: 576, 512) so each XCD's blocks share operand panels in L2.
__global__ __launch_bounds__(512, 4) void gemm_bt(
    const short* __restrict__ A, const short* __restrict__ Bw,
    float* __restrict__ C, int M, int N, int K)
{
    __shared__ short sA[2][128 * 32];
    __shared__ short sB[2][128 * 32];
    const int tid  = threadIdx.x;
    const int lane = tid & 63;
    const int wave = tid >> 6;          // 0..7
    const int wm = (wave >> 1) * 32;    // 4 row groups of 32
    const int wn = (wave & 1) * 64;     // 2 col groups of 64

    // XCD-aware swizzle: id = by*gx + bx; swz = (id&7)*(nwg/8) + id>>3
    const int nwg = gridDim.x * gridDim.y;
    const int id  = blockIdx.y * gridDim.x + blockIdx.x;
    const int swz = (id & 7) * (nwg >> 3) + (id >> 3);
    const int bx  = swz % gridDim.x;
    const int by  = swz / gridDim.x;
    const size_t row0 = (size_t)by * 128;
    const size_t col0 = (size_t)bx * 128;
    const int fr = lane & 15;
    const int fk = (lane >> 4) * 8;

    f32x4 acc[2][4] = {};

    const short* gA = A + (row0 + (tid >> 2)) * (size_t)K + (tid & 3) * 8;
    const short* gB = Bw + (col0 + (tid >> 2)) * (size_t)K + (tid & 3) * 8;
    const int loff = tid * 8;

    // prologue: stage k0 = 0 into buf 0 (one glds16 per operand)
    glds16(gA, sA[0] + loff);
    glds16(gB, sB[0] + loff);
    __syncthreads();

    int cur = 0;
    for (int k0 = 0; k0 < K; k0 += 32) {
        if (k0 + 32 < K) {
            const int nxt = cur ^ 1;
            glds16(gA + k0 + 32, sA[nxt] + loff);
            glds16(gB + k0 + 32, sB[nxt] + loff);
        }

        bf16x8 af[2], bb[4];
        #pragma unroll
        for (int m = 0; m < 2; ++m)
            af[m] = *(const bf16x8*)(sA[cur] + (wm + m * 16 + fr) * 32 + fk);
        #pragma unroll
        for (int n = 0; n < 4; ++n)
            bb[n] = *(const bf16x8*)(sB[cur] + (wn + n * 16 + fr) * 32 + fk);
        #pragma unroll
        for (int m = 0; m < 2; ++m)
            #pragma unroll
            for (int n = 0; n < 4; ++n)
                acc[m][n] = __builtin_amdgcn_mfma_f32_16x16x32_bf16(af[m], bb[n], acc[m][n], 0, 0, 0);

        __syncthreads();   // stage done (vmcnt) + all reads of buf[cur] done
        cur ^= 1;
    }

    const int cr = (lane >> 4) * 4;
    #pragma unroll
    for (int m = 0; m < 2; ++m)
        #pragma unroll
        for (int n = 0; n < 4; ++n)
            #pragma unroll
            for (int r = 0; r < 4; ++r)
                C[(row0 + wm + m * 16 + cr + r) * N + col0 + wn + n * 16 + fr] = acc[m][n][r];
}

// ---------- kernel 3: RoPE + RMSNorm; K/V written in MFMA-operand order ----
// kpack[b][tile=l/32][slot=d/16][lane=(d/8)%2*32 + l%32][e=d%8]  (16B/lane)
//   -> attention K-load = base + lane*16B : one contiguous 1-KB wave-load.
// vpack[b][chunk=kv/64][dt=d/32][sub=(kv/16)%4][lane=(kv/8)%2*32 + d%32][e=kv%8]
//   -> attention V-load likewise contiguous.
__global__ __launch_bounds__(256, 1) void prep_kernel(
    const float* __restrict__ qkv, const float* __restrict__ cosT,
    const float* __restrict__ sinT, short* __restrict__ qbf,
    short* __restrict__ kpack, short* __restrict__ vpack)
{
    const int row  = blockIdx.x;      // b*2048 + l
    const int b    = row >> 11;
    const int l    = row & 2047;
    const int wave = threadIdx.x >> 6;
    const int lane = threadIdx.x & 63;
    const float* src = qkv + (size_t)row * 2304;
    const float c = cosT[l * 64 + lane];
    const float s = sinT[l * 64 + lane];

    for (int hh = wave; hh < 18; hh += 4) {
        if (hh < 17) {
            const float* base = src + ((hh < 16) ? hh * 128 : 2048);
            float x1 = base[lane];
            float x2 = base[lane + 64];
            float y1 =  x1 * c + x2 * s;
            float y2 = -x1 * s + x2 * c;
            float ss = y1 * y1 + y2 * y2;
            #pragma unroll
            for (int m = 32; m >= 1; m >>= 1) ss += __shfl_xor(ss, m, 64);
            float sc = rsqrtf(ss * (1.0f / 128.0f) + EPS_RMS);
            if (hh < 16) {
                sc *= INV_SQRT_HD;
                short* dst = qbf + ((size_t)(b * 16 + hh) * 2048 + l) * 128;
                dst[lane]      = f2bf(y1 * sc);
                dst[lane + 64] = f2bf(y2 * sc);
            } else {
                // K element (row l, dim d) -> packed fragment order
                const size_t kb = ((size_t)b * 64 + (l >> 5)) * 4096 + (size_t)(l & 31) * 8;
                int d = lane;
                kpack[kb + (d >> 4) * 512 + ((d >> 3) & 1) * 256 + (d & 7)] = f2bf(y1 * sc);
                d = lane + 64;
                kpack[kb + (d >> 4) * 512 + ((d >> 3) & 1) * 256 + (d & 7)] = f2bf(y2 * sc);
            }
        } else {
            // V element (kv position l, dim d) -> packed fragment order
            const float* base = src + 2176;
            const size_t vb0 = ((size_t)(b * 32 + (l >> 6)) * 16 + ((l >> 4) & 3)) * 512
                             + ((l >> 3) & 1) * 256 + (l & 7);
            int d = lane;
            vpack[vb0 + (size_t)(d >> 5) * 2048 + (size_t)(d & 31) * 8] = f2bf(base[lane]);
            d = lane + 64;
            vpack[vb0 + (size_t)(d >> 5) * 2048 + (size_t)(d & 31) * 8] = f2bf(base[lane + 64]);
        }
    }
}

// ---------- attention chunk body (64 kv cols = two 32x32 tiles) ----------
// r16/r20-validated full-d version. All loads are contiguous 1-KB wave-loads
// from the packed layouts. Bounded scores (|s| <= ~11.4) -> P = exp(S), no
// max tracking. P^T -> B-operand via cvt_pk + permlane32_swap (T12).
template<bool MASKED, bool HAVET1>
__device__ __forceinline__ void attn_chunk(
    int j0, int gq, int hi, int lane,
    const short* __restrict__ kpB, const short* __restrict__ vpB,
    const bf16x8 (&qf)[8], f32x16 (&oacc)[4], float& lsum)
{
    union FragU { unsigned int u[4]; bf16x8 v; };

    const short* kt0 = kpB + (size_t)(j0 >> 5) * 4096 + lane * 8;
    const short* vtc = vpB + (size_t)(j0 >> 6) * 8192 + lane * 8;

    // ---- contiguous fragment loads ----
    bf16x8 k0[8], k1[8];
    #pragma unroll
    for (int s = 0; s < 8; ++s) k0[s] = *(const bf16x8*)(kt0 + s * 512);
    if (HAVET1) {
        #pragma unroll
        for (int s = 0; s < 8; ++s) k1[s] = *(const bf16x8*)(kt0 + 4096 + s * 512);
    }
    bf16x8 v0[8], v1[8];
    #pragma unroll
    for (int dt = 0; dt < 4; ++dt) {
        v0[2 * dt]     = *(const bf16x8*)(vtc + dt * 2048);
        v0[2 * dt + 1] = *(const bf16x8*)(vtc + dt * 2048 + 512);
        if (HAVET1) {
            v1[2 * dt]     = *(const bf16x8*)(vtc + dt * 2048 + 1024);
            v1[2 * dt + 1] = *(const bf16x8*)(vtc + dt * 2048 + 1536);
        }
    }

    // ---- S^T = K . Q^T ----
    f32x16 s0, s1;
    #pragma unroll
    for (int r = 0; r < 16; ++r) s0[r] = 0.f;
    #pragma unroll
    for (int s = 0; s < 8; ++s)
        s0 = __builtin_amdgcn_mfma_f32_32x32x16_bf16(k0[s], qf[s], s0, 0, 0, 0);
    if (HAVET1) {
        #pragma unroll
        for (int r = 0; r < 16; ++r) s1[r] = 0.f;
        #pragma unroll
        for (int s = 0; s < 8; ++s)
            s1 = __builtin_amdgcn_mfma_f32_32x32x16_bf16(k1[s], qf[s], s1, 0, 0, 0);
    }

    if (MASKED) {
        #pragma unroll
        for (int r = 0; r < 16; ++r) {
            const int base = (r & 3) + 8 * (r >> 2) + 4 * hi;
            if (j0 + base > gq) s0[r] = NEGBIG;
            if (HAVET1 && (j0 + 32 + base > gq)) s1[r] = NEGBIG;
        }
    }

    // P = exp(S)  (bounded scores; masked lanes underflow to 0)
    #pragma unroll
    for (int r = 0; r < 16; ++r) {
        s0[r] = __expf(s0[r]);
        if (HAVET1) s1[r] = __expf(s1[r]);
    }

    // per-lane half row sum (cross-half reduce deferred)
    {
        float a8[8];
        #pragma unroll
        for (int r = 0; r < 8; ++r)
            a8[r] = HAVET1 ? (s0[r] + s0[r + 8]) + (s1[r] + s1[r + 8])
                           : (s0[r] + s0[r + 8]);
        #pragma unroll
        for (int r = 0; r < 4; ++r) a8[r] += a8[r + 4];
        lsum += (a8[0] + a8[1]) + (a8[2] + a8[3]);
    }

    // P^T tile0 -> B-operand frags (cvt_pk + permlane32_swap), PV MFMA
    {
        unsigned int W[8];
        #pragma unroll
        for (int jw = 0; jw < 8; ++jw)
            W[jw] = cvtpk(s0[2 * jw], s0[2 * jw + 1]);
        FragU f0, f1;
        halfswap(W[0], W[2], f0.u[0], f0.u[2]);
        halfswap(W[1], W[3], f0.u[1], f0.u[3]);
        halfswap(W[4], W[6], f1.u[0], f1.u[2]);
        halfswap(W[5], W[7], f1.u[1], f1.u[3]);
        #pragma unroll
        for (int dt = 0; dt < 4; ++dt) {
            oacc[dt] = __builtin_amdgcn_mfma_f32_32x32x16_bf16(v0[2 * dt],     f0.v, oacc[dt], 0, 0, 0);
            oacc[dt] = __builtin_amdgcn_mfma_f32_32x32x16_bf16(v0[2 * dt + 1], f1.v, oacc[dt], 0, 0, 0);
        }
    }

    if (HAVET1) {
        unsigned int W[8];
        #pragma unroll
        for (int jw = 0; jw < 8; ++jw)
            W[jw] = cvtpk(s1[2 * jw], s1[2 * jw + 1]);
        FragU f2, f3;
        halfswap(W[0], W[2], f2.u[0], f2.u[2]);
        halfswap(W[1], W[3], f2.u[1], f2.u[3]);
        halfswap(W[4], W[6], f3.u[0], f3.u[2]);
        halfswap(W[5], W[7], f3.u[1], f3.u[3]);
        #pragma unroll
        for (int dt = 0; dt < 4; ++dt) {
            oacc[dt] = __builtin_amdgcn_mfma_f32_32x32x16_bf16(v1[2 * dt],     f2.v, oacc[dt], 0, 0, 0);
            oacc[dt] = __builtin_amdgcn_mfma_f32_32x32x16_bf16(v1[2 * dt + 1], f3.v, oacc[dt], 0, 0, 0);
        }
    }
}

// ---------- kernel 4: causal MQA flash attention, balanced tile pairs ----------
// Grid (32 heads, 32 pairs) x 128 threads (2 INDEPENDENT waves). Wave 0 ->
// tile 63-p (long), wave 1 -> tile p (short): per-block work is ~constant
// (C(p)+C(63-p) ~ 33 chunks), so residency stays 2 waves/SIMD for the WHOLE
// kernel instead of decaying as short causal tiles retire (r20: avg 3.8 of 8
// assigned waves/CU). Per-wave code is byte-identical to the r20-validated
// kernel; waves share nothing (wave-private o_sh halves, one barrier).
__global__ __launch_bounds__(128, 2) void attn_kernel(
    const short* __restrict__ qbf, const short* __restrict__ kpack,
    const short* __restrict__ vpack, short* __restrict__ obf)
{
    __shared__ short o_sh[2][32][136];   // +8 pad: conflict-free epilogue
    const int tid  = threadIdx.x;
    const int wave = tid >> 6;
    const int lane = tid & 63;
    const int l31  = lane & 31;
    const int hi   = lane >> 5;

    const int gh = blockIdx.x;                 // 0..31 = b*16+h
    const int b  = gh >> 4;
    const int h  = gh & 15;
    const int p  = blockIdx.y;                 // 0..31
    const int tile = (wave == 0) ? (63 - p) : p;   // balanced pair
    const int q0 = tile * 32;
    const int gq = q0 + l31;                   // this lane's q row

    const short* qp  = qbf + ((size_t)gh * 2048 + gq) * 128 + hi * 8;
    const short* kpB = kpack + (size_t)b * 64 * 4096;
    const short* vpB = vpack + (size_t)b * 32 * 8192;

    // Q fragments: B-operand of S^T (col = q). 8 k-slots of 16 over hd=128.
    bf16x8 qf[8];
    #pragma unroll
    for (int s = 0; s < 8; ++s) qf[s] = *(const bf16x8*)(qp + s * 16);

    f32x16 oacc[4];
    #pragma unroll
    for (int dt = 0; dt < 4; ++dt)
        #pragma unroll
        for (int r = 0; r < 16; ++r) oacc[dt][r] = 0.f;
    float lsum = 0.f;

    // steady state: full unmasked chunks (j0+63 <= q0 for all lanes' gq)
    int j0 = 0;
    for (; j0 < q0 - 32; j0 += 64)
        attn_chunk<false, true>(j0, gq, hi, lane, kpB, vpB, qf, oacc, lsum);
    // exactly one diagonal (masked) tail chunk: j0 <= q0 < j0+64 here
    if (j0 < q0) attn_chunk<true, true >(j0, gq, hi, lane, kpB, vpB, qf, oacc, lsum);
    else         attn_chunk<true, false>(j0, gq, hi, lane, kpB, vpB, qf, oacc, lsum);

    // complete the deferred cross-half row-sum reduce
    lsum += __shfl_xor(lsum, 32);

    // ---- epilogue: normalize, transpose via LDS (wave-private), store ----
    const float inv = 1.0f / lsum;
    #pragma unroll
    for (int dt = 0; dt < 4; ++dt)
        #pragma unroll
        for (int r = 0; r < 16; ++r) {
            const int d = dt * 32 + (r & 3) + 8 * (r >> 2) + 4 * hi;
            o_sh[wave][l31][d] = f2bf(oacc[dt][r] * inv);
        }
    __syncthreads();
    const int rlane = lane >> 4;       // 0..3
    const int dl = (lane & 15) * 8;
    #pragma unroll
    for (int pass = 0; pass < 8; ++pass) {
        const int row = pass * 4 + rlane;
        bf16x8 ov = *(const bf16x8*)(&o_sh[wave][row][dl]);
        *(bf16x8*)(obf + ((size_t)b * 2048 + q0 + row) * 2048 + h * 128 + dl) = ov;
    }
}

// ---------- launch ----------
extern "C" void kernel_launch(void* const* d_in, const int* in_sizes, int n_in,
                              void* d_out, int out_size, void* d_ws, size_t ws_size,
                              hipStream_t stream)
{
    const float* x    = (const float*)d_in[0];
    const float* cosT = (const float*)d_in[1];
    const float* sinT = (const float*)d_in[2];
    const float* wq   = (const float*)d_in[3];
    const float* wk   = (const float*)d_in[4];
    const float* wv   = (const float*)d_in[5];
    const float* wo   = (const float*)d_in[6];
    float* out = (float*)d_out;

    char* ws = (char*)d_ws;
    size_t off = 0;
    auto alloc = [&](size_t bytes) {
        char* p = ws + off;
        off = (off + bytes + 255) & ~(size_t)255;
        return p;
    };
    short* x_bf  = (short*)alloc((size_t)4096 * 2048 * 2);   // also reused as attn_bf
    short* wcat  = (short*)alloc((size_t)2304 * 2048 * 2);   // [wq;wk;wv]
    short* wo_bf = (short*)alloc((size_t)2048 * 2048 * 2);
    float* qkv   = (float*)alloc((size_t)4096 * 2304 * 4);
    short* q_bf  = (short*)alloc((size_t)2 * 16 * 2048 * 128 * 2);
    short* kpack = (short*)alloc((size_t)2 * 64 * 4096 * 2);  // K, fragment order
    short* vpack = (short*)alloc((size_t)2 * 32 * 8192 * 2);  // V^T, fragment order
    short* attn_bf = x_bf;  // x_bf dead after GEMM1; alias to save workspace
    (void)in_sizes; (void)n_in; (void)out_size; (void)ws_size;

    cvt_f32_bf16<<<1024, 256, 0, stream>>>(x, x_bf, 4096 * 2048);
    cvt_f32_bf16<<<512, 256, 0, stream>>>(wq, wcat, 2048 * 2048);
    cvt_f32_bf16<<<64, 256, 0, stream>>>(wk, wcat + (size_t)2048 * 2048, 128 * 2048);
    cvt_f32_bf16<<<64, 256, 0, stream>>>(wv, wcat + (size_t)2176 * 2048, 128 * 2048);
    cvt_f32_bf16<<<512, 256, 0, stream>>>(wo, wo_bf, 2048 * 2048);

    // qkv = x @ [wq;wk;wv]^T   (M=4096, N=2304, K=2048)
    gemm_bt<<<dim3(18, 32), 512, 0, stream>>>(x_bf, wcat, qkv, 4096, 2304, 2048);

    prep_kernel<<<4096, 256, 0, stream>>>(qkv, cosT, sinT, q_bf, kpack, vpack);

    attn_kernel<<<dim3(32, 32), 128, 0, stream>>>(q_bf, kpack, vpack, attn_bf);

    // out = attn @ wo^T   (M=4096, N=2048, K=2048)
    gemm_bt<<<dim3(16, 32), 512, 0, stream>>>(attn_bf, wo_bf, out, 4096, 2048, 2048);
}

// Round 22
// 202.739 us; speedup vs baseline: 1.1436x; 1.1436x over previous
//
#include <hip/hip_runtime.h>
#include <stdint.h>

// ---------- types ----------
typedef short bf16x8 __attribute__((ext_vector_type(8)));
typedef float f32x4  __attribute__((ext_vector_type(4)));
typedef float f32x16 __attribute__((ext_vector_type(16)));
typedef int   i32x2  __attribute__((ext_vector_type(2)));

#define EPS_RMS 1.1920929e-07f
#define INV_SQRT_HD 0.08838834764831845f  // 1/sqrt(128)
#define NEGBIG (-3.0e38f)

// f32 -> bf16 bits, round-to-nearest-even (scalar, epilogue/convert use)
__device__ __forceinline__ short f2bf(float f) {
    uint32_t u = __float_as_uint(f);
    u += 0x7fffu + ((u >> 16) & 1u);
    return (short)(u >> 16);
}

// packed f32x2 -> bf16x2 in one VALU op (T12 recipe; no builtin on gfx950)
__device__ __forceinline__ unsigned int cvtpk(float lo, float hi) {
    unsigned int r;
    asm("v_cvt_pk_bf16_f32 %0, %1, %2" : "=v"(r) : "v"(lo), "v"(hi));
    return r;
}

// v_permlane32_swap_b32: x = {a.lo | b.lo->hi}, y = {a.hi->lo | b.hi}
__device__ __forceinline__ void halfswap(unsigned int a, unsigned int b,
                                         unsigned int& x, unsigned int& y) {
    i32x2 r = __builtin_amdgcn_permlane32_swap((int)a, (int)b, false, false);
    x = (unsigned int)r.x;
    y = (unsigned int)r.y;
}

using gld_t = const __attribute__((address_space(1))) unsigned int*;
using lds_t = __attribute__((address_space(3))) unsigned int*;

// async global->LDS, 16 bytes per lane (lane i lands at ldsbase + i*16)
__device__ __forceinline__ void glds16(const short* g, short* l) {
    __builtin_amdgcn_global_load_lds((gld_t)g, (lds_t)l, 16, 0, 0);
}

// ---------- kernel 1: f32 -> bf16 convert (vectorized x4) ----------
__global__ void cvt_f32_bf16(const float* __restrict__ in, short* __restrict__ out, int n) {
    int i = (blockIdx.x * blockDim.x + threadIdx.x) * 4;
    int stride = gridDim.x * blockDim.x * 4;
    for (; i < n; i += stride) {
        float4 v = *(const float4*)(in + i);
        short4 o;
        o.x = f2bf(v.x); o.y = f2bf(v.y); o.z = f2bf(v.z); o.w = f2bf(v.w);
        *(short4*)(out + i) = o;
    }
}

// ---------- kernel 2: C[M,N] = A[M,K] * Bw[N,K]^T  (bf16 in, f32 out) ----------
// 8-wave (512-thread) 128x128 block, wave tile 32x64; double-buffered LDS,
// stage tile t+1 BEFORE computing tile t, ONE barrier per K-step. Staging is
// a single glds16 per operand tile (512 lanes x 16B = 128x32 bf16).
// T1 XCD swizzle: bijective block->tile remap (requires nwg % 8 == 0; both
// grids satisfy: 576, 512) so each XCD's blocks share operand panels in L2.
__global__ __launch_bounds__(512, 4) void gemm_bt(
    const short* __restrict__ A, const short* __restrict__ Bw,
    float* __restrict__ C, int M, int N, int K)
{
    __shared__ short sA[2][128 * 32];
    __shared__ short sB[2][128 * 32];
    const int tid  = threadIdx.x;
    const int lane = tid & 63;
    const int wave = tid >> 6;          // 0..7
    const int wm = (wave >> 1) * 32;    // 4 row groups of 32
    const int wn = (wave & 1) * 64;     // 2 col groups of 64

    // XCD-aware swizzle: id = by*gx + bx; swz = (id&7)*(nwg/8) + id>>3
    const int nwg = gridDim.x * gridDim.y;
    const int id  = blockIdx.y * gridDim.x + blockIdx.x;
    const int swz = (id & 7) * (nwg >> 3) + (id >> 3);
    const int bx  = swz % gridDim.x;
    const int by  = swz / gridDim.x;
    const size_t row0 = (size_t)by * 128;
    const size_t col0 = (size_t)bx * 128;
    const int fr = lane & 15;
    const int fk = (lane >> 4) * 8;

    f32x4 acc[2][4] = {};

    const short* gA = A + (row0 + (tid >> 2)) * (size_t)K + (tid & 3) * 8;
    const short* gB = Bw + (col0 + (tid >> 2)) * (size_t)K + (tid & 3) * 8;
    const int loff = tid * 8;

    // prologue: stage k0 = 0 into buf 0 (one glds16 per operand)
    glds16(gA, sA[0] + loff);
    glds16(gB, sB[0] + loff);
    __syncthreads();

    int cur = 0;
    for (int k0 = 0; k0 < K; k0 += 32) {
        if (k0 + 32 < K) {
            const int nxt = cur ^ 1;
            glds16(gA + k0 + 32, sA[nxt] + loff);
            glds16(gB + k0 + 32, sB[nxt] + loff);
        }

        bf16x8 af[2], bb[4];
        #pragma unroll
        for (int m = 0; m < 2; ++m)
            af[m] = *(const bf16x8*)(sA[cur] + (wm + m * 16 + fr) * 32 + fk);
        #pragma unroll
        for (int n = 0; n < 4; ++n)
            bb[n] = *(const bf16x8*)(sB[cur] + (wn + n * 16 + fr) * 32 + fk);
        #pragma unroll
        for (int m = 0; m < 2; ++m)
            #pragma unroll
            for (int n = 0; n < 4; ++n)
                acc[m][n] = __builtin_amdgcn_mfma_f32_16x16x32_bf16(af[m], bb[n], acc[m][n], 0, 0, 0);

        __syncthreads();   // stage done (vmcnt) + all reads of buf[cur] done
        cur ^= 1;
    }

    const int cr = (lane >> 4) * 4;
    #pragma unroll
    for (int m = 0; m < 2; ++m)
        #pragma unroll
        for (int n = 0; n < 4; ++n)
            #pragma unroll
            for (int r = 0; r < 4; ++r)
                C[(row0 + wm + m * 16 + cr + r) * N + col0 + wn + n * 16 + fr] = acc[m][n][r];
}

// ---------- kernel 3: RoPE + RMSNorm; K/V written in MFMA-operand order ----
// kpack[b][tile=l/32][slot=d/16][lane=(d/8)%2*32 + l%32][e=d%8]  (16B/lane)
//   -> attention K-load = base + lane*16B : one contiguous 1-KB wave-load.
// vpack[b][chunk=kv/64][dt=d/32][sub=(kv/16)%4][lane=(kv/8)%2*32 + d%32][e=kv%8]
//   -> attention V-load likewise contiguous.
__global__ __launch_bounds__(256, 1) void prep_kernel(
    const float* __restrict__ qkv, const float* __restrict__ cosT,
    const float* __restrict__ sinT, short* __restrict__ qbf,
    short* __restrict__ kpack, short* __restrict__ vpack)
{
    const int row  = blockIdx.x;      // b*2048 + l
    const int b    = row >> 11;
    const int l    = row & 2047;
    const int wave = threadIdx.x >> 6;
    const int lane = threadIdx.x & 63;
    const float* src = qkv + (size_t)row * 2304;
    const float c = cosT[l * 64 + lane];
    const float s = sinT[l * 64 + lane];

    for (int hh = wave; hh < 18; hh += 4) {
        if (hh < 17) {
            const float* base = src + ((hh < 16) ? hh * 128 : 2048);
            float x1 = base[lane];
            float x2 = base[lane + 64];
            float y1 =  x1 * c + x2 * s;
            float y2 = -x1 * s + x2 * c;
            float ss = y1 * y1 + y2 * y2;
            #pragma unroll
            for (int m = 32; m >= 1; m >>= 1) ss += __shfl_xor(ss, m, 64);
            float sc = rsqrtf(ss * (1.0f / 128.0f) + EPS_RMS);
            if (hh < 16) {
                sc *= INV_SQRT_HD;
                short* dst = qbf + ((size_t)(b * 16 + hh) * 2048 + l) * 128;
                dst[lane]      = f2bf(y1 * sc);
                dst[lane + 64] = f2bf(y2 * sc);
            } else {
                // K element (row l, dim d) -> packed fragment order
                const size_t kb = ((size_t)b * 64 + (l >> 5)) * 4096 + (size_t)(l & 31) * 8;
                int d = lane;
                kpack[kb + (d >> 4) * 512 + ((d >> 3) & 1) * 256 + (d & 7)] = f2bf(y1 * sc);
                d = lane + 64;
                kpack[kb + (d >> 4) * 512 + ((d >> 3) & 1) * 256 + (d & 7)] = f2bf(y2 * sc);
            }
        } else {
            // V element (kv position l, dim d) -> packed fragment order
            const float* base = src + 2176;
            const size_t vb0 = ((size_t)(b * 32 + (l >> 6)) * 16 + ((l >> 4) & 3)) * 512
                             + ((l >> 3) & 1) * 256 + (l & 7);
            int d = lane;
            vpack[vb0 + (size_t)(d >> 5) * 2048 + (size_t)(d & 31) * 8] = f2bf(base[lane]);
            d = lane + 64;
            vpack[vb0 + (size_t)(d >> 5) * 2048 + (size_t)(d & 31) * 8] = f2bf(base[lane + 64]);
        }
    }
}

// ---------- attention chunk body (64 kv cols = two 32x32 tiles) ----------
// r16/r20-validated full-d version. All loads are contiguous 1-KB wave-loads
// from the packed layouts. Bounded scores (|s| <= ~11.4) -> P = exp(S), no
// max tracking. P^T -> B-operand via cvt_pk + permlane32_swap (T12).
template<bool MASKED, bool HAVET1>
__device__ __forceinline__ void attn_chunk(
    int j0, int gq, int hi, int lane,
    const short* __restrict__ kpB, const short* __restrict__ vpB,
    const bf16x8 (&qf)[8], f32x16 (&oacc)[4], float& lsum)
{
    union FragU { unsigned int u[4]; bf16x8 v; };

    const short* kt0 = kpB + (size_t)(j0 >> 5) * 4096 + lane * 8;
    const short* vtc = vpB + (size_t)(j0 >> 6) * 8192 + lane * 8;

    // ---- contiguous fragment loads ----
    bf16x8 k0[8], k1[8];
    #pragma unroll
    for (int s = 0; s < 8; ++s) k0[s] = *(const bf16x8*)(kt0 + s * 512);
    if (HAVET1) {
        #pragma unroll
        for (int s = 0; s < 8; ++s) k1[s] = *(const bf16x8*)(kt0 + 4096 + s * 512);
    }
    bf16x8 v0[8], v1[8];
    #pragma unroll
    for (int dt = 0; dt < 4; ++dt) {
        v0[2 * dt]     = *(const bf16x8*)(vtc + dt * 2048);
        v0[2 * dt + 1] = *(const bf16x8*)(vtc + dt * 2048 + 512);
        if (HAVET1) {
            v1[2 * dt]     = *(const bf16x8*)(vtc + dt * 2048 + 1024);
            v1[2 * dt + 1] = *(const bf16x8*)(vtc + dt * 2048 + 1536);
        }
    }

    // ---- S^T = K . Q^T ----
    f32x16 s0, s1;
    #pragma unroll
    for (int r = 0; r < 16; ++r) s0[r] = 0.f;
    #pragma unroll
    for (int s = 0; s < 8; ++s)
        s0 = __builtin_amdgcn_mfma_f32_32x32x16_bf16(k0[s], qf[s], s0, 0, 0, 0);
    if (HAVET1) {
        #pragma unroll
        for (int r = 0; r < 16; ++r) s1[r] = 0.f;
        #pragma unroll
        for (int s = 0; s < 8; ++s)
            s1 = __builtin_amdgcn_mfma_f32_32x32x16_bf16(k1[s], qf[s], s1, 0, 0, 0);
    }

    if (MASKED) {
        #pragma unroll
        for (int r = 0; r < 16; ++r) {
            const int base = (r & 3) + 8 * (r >> 2) + 4 * hi;
            if (j0 + base > gq) s0[r] = NEGBIG;
            if (HAVET1 && (j0 + 32 + base > gq)) s1[r] = NEGBIG;
        }
    }

    // P = exp(S)  (bounded scores; masked lanes underflow to 0)
    #pragma unroll
    for (int r = 0; r < 16; ++r) {
        s0[r] = __expf(s0[r]);
        if (HAVET1) s1[r] = __expf(s1[r]);
    }

    // per-lane half row sum (cross-half reduce deferred)
    {
        float a8[8];
        #pragma unroll
        for (int r = 0; r < 8; ++r)
            a8[r] = HAVET1 ? (s0[r] + s0[r + 8]) + (s1[r] + s1[r + 8])
                           : (s0[r] + s0[r + 8]);
        #pragma unroll
        for (int r = 0; r < 4; ++r) a8[r] += a8[r + 4];
        lsum += (a8[0] + a8[1]) + (a8[2] + a8[3]);
    }

    // P^T tile0 -> B-operand frags (cvt_pk + permlane32_swap), PV MFMA
    {
        unsigned int W[8];
        #pragma unroll
        for (int jw = 0; jw < 8; ++jw)
            W[jw] = cvtpk(s0[2 * jw], s0[2 * jw + 1]);
        FragU f0, f1;
        halfswap(W[0], W[2], f0.u[0], f0.u[2]);
        halfswap(W[1], W[3], f0.u[1], f0.u[3]);
        halfswap(W[4], W[6], f1.u[0], f1.u[2]);
        halfswap(W[5], W[7], f1.u[1], f1.u[3]);
        #pragma unroll
        for (int dt = 0; dt < 4; ++dt) {
            oacc[dt] = __builtin_amdgcn_mfma_f32_32x32x16_bf16(v0[2 * dt],     f0.v, oacc[dt], 0, 0, 0);
            oacc[dt] = __builtin_amdgcn_mfma_f32_32x32x16_bf16(v0[2 * dt + 1], f1.v, oacc[dt], 0, 0, 0);
        }
    }

    if (HAVET1) {
        unsigned int W[8];
        #pragma unroll
        for (int jw = 0; jw < 8; ++jw)
            W[jw] = cvtpk(s1[2 * jw], s1[2 * jw + 1]);
        FragU f2, f3;
        halfswap(W[0], W[2], f2.u[0], f2.u[2]);
        halfswap(W[1], W[3], f2.u[1], f2.u[3]);
        halfswap(W[4], W[6], f3.u[0], f3.u[2]);
        halfswap(W[5], W[7], f3.u[1], f3.u[3]);
        #pragma unroll
        for (int dt = 0; dt < 4; ++dt) {
            oacc[dt] = __builtin_amdgcn_mfma_f32_32x32x16_bf16(v1[2 * dt],     f2.v, oacc[dt], 0, 0, 0);
            oacc[dt] = __builtin_amdgcn_mfma_f32_32x32x16_bf16(v1[2 * dt + 1], f3.v, oacc[dt], 0, 0, 0);
        }
    }
}

// ---------- kernel 4: causal MQA flash attention, one wave per q-tile ----------
// Grid (32 heads, 64 q-tiles), 64-thread blocks, longest tiles first; 2048
// independent single-wave blocks -> no cross-wave communication anywhere,
// deterministic by construction. S^T = mfma(K, Q^T): lane&31 = q row,
// lane-local softmax; O^T = mfma(V^T, P^T). Epilogue: per-wave LDS transpose.
__global__ __launch_bounds__(64, 2) void attn_kernel(
    const short* __restrict__ qbf, const short* __restrict__ kpack,
    const short* __restrict__ vpack, short* __restrict__ obf)
{
    __shared__ short o_sh[32][136];   // +8 pad: conflict-free epilogue
    const int lane = threadIdx.x & 63;
    const int l31  = lane & 31;
    const int hi   = lane >> 5;

    const int gh = blockIdx.x;                 // 0..31 = b*16+h
    const int b  = gh >> 4;
    const int h  = gh & 15;
    const int tile = 63 - blockIdx.y;          // longest tiles dispatch first
    const int q0 = tile * 32;
    const int gq = q0 + l31;                   // this lane's q row

    const short* qp  = qbf + ((size_t)gh * 2048 + gq) * 128 + hi * 8;
    const short* kpB = kpack + (size_t)b * 64 * 4096;
    const short* vpB = vpack + (size_t)b * 32 * 8192;

    // Q fragments: B-operand of S^T (col = q). 8 k-slots of 16 over hd=128.
    bf16x8 qf[8];
    #pragma unroll
    for (int s = 0; s < 8; ++s) qf[s] = *(const bf16x8*)(qp + s * 16);

    f32x16 oacc[4];
    #pragma unroll
    for (int dt = 0; dt < 4; ++dt)
        #pragma unroll
        for (int r = 0; r < 16; ++r) oacc[dt][r] = 0.f;
    float lsum = 0.f;

    // steady state: full unmasked chunks (j0+63 <= q0 for all lanes' gq)
    int j0 = 0;
    for (; j0 < q0 - 32; j0 += 64)
        attn_chunk<false, true>(j0, gq, hi, lane, kpB, vpB, qf, oacc, lsum);
    // exactly one diagonal (masked) tail chunk: j0 <= q0 < j0+64 here
    if (j0 < q0) attn_chunk<true, true >(j0, gq, hi, lane, kpB, vpB, qf, oacc, lsum);
    else         attn_chunk<true, false>(j0, gq, hi, lane, kpB, vpB, qf, oacc, lsum);

    // complete the deferred cross-half row-sum reduce
    lsum += __shfl_xor(lsum, 32);

    // ---- epilogue: normalize, transpose via LDS (wave-private), store ----
    const float inv = 1.0f / lsum;
    #pragma unroll
    for (int dt = 0; dt < 4; ++dt)
        #pragma unroll
        for (int r = 0; r < 16; ++r) {
            const int d = dt * 32 + (r & 3) + 8 * (r >> 2) + 4 * hi;
            o_sh[l31][d] = f2bf(oacc[dt][r] * inv);
        }
    __syncthreads();
    const int rlane = lane >> 4;       // 0..3
    const int dl = (lane & 15) * 8;
    #pragma unroll
    for (int pass = 0; pass < 8; ++pass) {
        const int row = pass * 4 + rlane;
        bf16x8 ov = *(const bf16x8*)(&o_sh[row][dl]);
        *(bf16x8*)(obf + ((size_t)b * 2048 + q0 + row) * 2048 + h * 128 + dl) = ov;
    }
}

// ---------- launch ----------
extern "C" void kernel_launch(void* const* d_in, const int* in_sizes, int n_in,
                              void* d_out, int out_size, void* d_ws, size_t ws_size,
                              hipStream_t stream)
{
    const float* x    = (const float*)d_in[0];
    const float* cosT = (const float*)d_in[1];
    const float* sinT = (const float*)d_in[2];
    const float* wq   = (const float*)d_in[3];
    const float* wk   = (const float*)d_in[4];
    const float* wv   = (const float*)d_in[5];
    const float* wo   = (const float*)d_in[6];
    float* out = (float*)d_out;

    char* ws = (char*)d_ws;
    size_t off = 0;
    auto alloc = [&](size_t bytes) {
        char* p = ws + off;
        off = (off + bytes + 255) & ~(size_t)255;
        return p;
    };
    short* x_bf  = (short*)alloc((size_t)4096 * 2048 * 2);   // also reused as attn_bf
    short* wcat  = (short*)alloc((size_t)2304 * 2048 * 2);   // [wq;wk;wv]
    short* wo_bf = (short*)alloc((size_t)2048 * 2048 * 2);
    float* qkv   = (float*)alloc((size_t)4096 * 2304 * 4);
    short* q_bf  = (short*)alloc((size_t)2 * 16 * 2048 * 128 * 2);
    short* kpack = (short*)alloc((size_t)2 * 64 * 4096 * 2);  // K, fragment order
    short* vpack = (short*)alloc((size_t)2 * 32 * 8192 * 2);  // V^T, fragment order
    short* attn_bf = x_bf;  // x_bf dead after GEMM1; alias to save workspace
    (void)in_sizes; (void)n_in; (void)out_size; (void)ws_size;

    cvt_f32_bf16<<<1024, 256, 0, stream>>>(x, x_bf, 4096 * 2048);
    cvt_f32_bf16<<<512, 256, 0, stream>>>(wq, wcat, 2048 * 2048);
    cvt_f32_bf16<<<64, 256, 0, stream>>>(wk, wcat + (size_t)2048 * 2048, 128 * 2048);
    cvt_f32_bf16<<<64, 256, 0, stream>>>(wv, wcat + (size_t)2176 * 2048, 128 * 2048);
    cvt_f32_bf16<<<512, 256, 0, stream>>>(wo, wo_bf, 2048 * 2048);

    // qkv = x @ [wq;wk;wv]^T   (M=4096, N=2304, K=2048)
    gemm_bt<<<dim3(18, 32), 512, 0, stream>>>(x_bf, wcat, qkv, 4096, 2304, 2048);

    prep_kernel<<<4096, 256, 0, stream>>>(qkv, cosT, sinT, q_bf, kpack, vpack);

    attn_kernel<<<dim3(32, 64), 64, 0, stream>>>(q_bf, kpack, vpack, attn_bf);

    // out = attn @ wo^T   (M=4096, N=2048, K=2048)
    gemm_bt<<<dim3(16, 32), 512, 0, stream>>>(attn_bf, wo_bf, out, 4096, 2048, 2048);
}